// Round 10
// baseline (2509.696 us; speedup 1.0000x reference)
//
#include <hip/hip_runtime.h>
#include <hip/hip_fp16.h>
#include <cstdint>

typedef _Float16 f16x8 __attribute__((ext_vector_type(8)));
typedef float f32x4 __attribute__((ext_vector_type(4)));
typedef int i32x4 __attribute__((ext_vector_type(4)));

// B=64, T=1024, IN=256, HID=256. Column c = 4u + gi (gi: 0=i,1=f,2=o,3=c).
// lstm_rec: 4 WGs x 1024 thr (16 waves = 4/SIMD); WG g owns batches [16g,16g+16).
// TRANSPOSED MFMA: D[col][batch] = W^T(i8) . h^T(i8), mfma_i32_16x16x64_i8, 4 ktiles.
// Wave w (0..15) owns mtiles 4w..4w+3 (units 16w..16w+15). Lane: batch=l&15, rg=l>>4;
// acc[reg] for mt = gates gi=reg of unit u=16w+4mt+rg -> fully in-lane cell update.
// xg PRE-SCALED per gate: i/f/o x -1.44269504, c x +2.88539008 (exp2-ready).
// K-permutation: source-unit at k is us(k)=16(k>>4)+4(k&3)+((k>>2)&3) so the 4 rg
// lanes write 4 distinct LDS dwords; h bytes packed -> ONE ds_write_b32/thread/step.

#define XG_OFF    0ULL
#define XG_BYTES  134217728ULL   // xgp[t][g][w16][l][mt4][gi4] fp16 (32B/lane/t)
#define AP_OFF    (XG_OFF + XG_BYTES)
#define AP_BYTES  33554432ULL
#define BP_OFF    (AP_OFF + AP_BYTES)
#define BP_BYTES  524288ULL
#define WAP_OFF   (BP_OFF + BP_BYTES)
#define WAP_BYTES 262144ULL      // int8 A-frags: [M64][kt4][l64][16]
#define BIAS_OFF  (WAP_OFF + WAP_BYTES)

#define GLOROT 0.08838834764831845f
#define CSC    (GLOROT / 16129.0f)            // s_w * s_h
#define CSCI   (-1.44269504f * CSC)           // sigmoid gates (pre-scaled)
#define CSCC   (2.88539008f * CSC)            // candidate gate (pre-scaled)
#define QINV   (127.0f / GLOROT)

#define EXP2(x) __builtin_amdgcn_exp2f(x)
#define RCP(x)  __builtin_amdgcn_rcpf(x)

// ---------------- Phase 0: pack weights (i8 A-frags + f16 B-frags for x-GEMM + bias) ---
__global__ void pack_weights(const float* __restrict__ Wi, const float* __restrict__ Wf,
                             const float* __restrict__ Wo, const float* __restrict__ Wc,
                             const float* __restrict__ bi, const float* __restrict__ bf,
                             const float* __restrict__ bo, const float* __restrict__ bc,
                             int8_t* __restrict__ WAp, __half* __restrict__ Bp,
                             float* __restrict__ bias_eff)
{
    int tidg = blockIdx.x * blockDim.x + threadIdx.x;
    if (tidg < 262144) {
        // WAp[((M*4+kt)*64+l)*16+i] = q(Wh_gi[us(k)][u]), c=16M+(l&15)
        int i  = tidg & 15;
        int l  = (tidg >> 4) & 63;
        int kt = (tidg >> 10) & 3;
        int M  = tidg >> 12;
        int c  = 16 * M + (l & 15);
        int u  = c >> 2, gi = c & 3;
        int khi = kt * 4 + (l >> 4);                 // k>>4
        int us  = 16 * khi + 4 * (i & 3) + (i >> 2); // permuted source unit
        const float* W = (gi == 0) ? Wi : (gi == 1) ? Wf : (gi == 2) ? Wo : Wc;
        float q = rintf(W[us * 256 + u] * QINV);     // h-part rows [0,256)
        q = fminf(127.f, fmaxf(-127.f, q));
        WAp[tidg] = (int8_t)(int)q;
    } else if (tidg < 262144 + 262144) {
        // Bp for x-GEMM: c = n*16+(l&15); u=c>>2, g=c&3; x-part rows [256,512)
        int beta = tidg - 262144;
        int i = beta & 7;
        int l = (beta >> 3) & 63;
        int kk = (beta >> 9) & 7;
        int n = beta >> 12;
        int c = n * 16 + (l & 15);
        int u = c >> 2, g = c & 3;
        int k = kk * 32 + (l >> 4) * 8 + i;
        const float* W = (g == 0) ? Wi : (g == 1) ? Wf : (g == 2) ? Wo : Wc;
        Bp[beta] = __float2half(W[(256 + k) * 256 + u]);
    } else if (tidg < 262144 + 262144 + 1024) {
        int c = tidg - 524288;
        int g = c & 3;
        const float* bb = (g == 0) ? bi : (g == 1) ? bf : (g == 2) ? bo : bc;
        bias_eff[c] = bb[c >> 2];
    }
}

// ---------------- Phase 0b: pack x into A fragments (f16 GEMM) ----------------
__global__ void pack_a(const float* __restrict__ x, __half* __restrict__ Ap)
{
    int t = blockIdx.x * blockDim.x + threadIdx.x;
    int l  = t & 63;
    int kk = (t >> 6) & 7;
    int m  = t >> 9;
    int row = m * 16 + (l & 15);
    int k0  = kk * 32 + (l >> 4) * 8;
    const float* src = x + (size_t)row * 256 + k0;
    f16x8 v;
#pragma unroll
    for (int i = 0; i < 8; ++i) v[i] = (_Float16)src[i];
    *reinterpret_cast<f16x8*>(Ap + (size_t)t * 8) = v;
}

// ---------------- Phase 1: xg = (x @ Wx + bias) * gate_scale, lstm per-lane layout -----
__global__ __launch_bounds__(256) void gemm_xg(const __half* __restrict__ Ap,
                                               const __half* __restrict__ Bp,
                                               const float* __restrict__ bias_eff,
                                               __half* __restrict__ xgh)
{
    int wave = threadIdx.x >> 6;
    int lane = threadIdx.x & 63;
    int mtile = blockIdx.x * 4 + wave;
    int ntbase = blockIdx.y * 16;

    f16x8 a[8];
#pragma unroll
    for (int kk = 0; kk < 8; ++kk)
        a[kk] = *reinterpret_cast<const f16x8*>(Ap + ((size_t)(mtile * 8 + kk) * 64 + lane) * 8);

    int col_lo = lane & 15;
    int rgrp = lane >> 4;
#pragma unroll 1
    for (int j = 0; j < 16; ++j) {
        int nt = ntbase + j;
        int c = nt * 16 + col_lo;
        float bb = bias_eff[c];
        f32x4 acc = {bb, bb, bb, bb};
#pragma unroll
        for (int kk = 0; kk < 8; ++kk) {
            f16x8 bfr = *reinterpret_cast<const f16x8*>(Bp + ((size_t)(nt * 8 + kk) * 64 + lane) * 8);
            acc = __builtin_amdgcn_mfma_f32_16x16x32_f16(a[kk], bfr, acc, 0, 0, 0);
        }
        int u = c >> 2, gi = c & 3;
        float gsc = (gi == 3) ? 2.88539008f : -1.44269504f;
        int M2 = u >> 2, rga = u & 3;
        int wv = M2 >> 2, mt = M2 & 3;
#pragma unroll
        for (int r2 = 0; r2 < 4; ++r2) {
            int row = mtile * 16 + rgrp * 4 + r2;
            int b = row >> 10, t = row & 1023;
            int gW = b >> 4, bl = b & 15;
            size_t idx = ((((size_t)(t * 4 + gW) * 16 + wv) * 64 + (rga * 16 + bl)) * 4 + mt) * 4 + gi;
            xgh[idx] = __float2half(acc[r2] * gsc);
        }
    }
}

// ---------------- Phase 2: recurrence, 4 WGs x 1024 thr, raw lgkm barrier --------------
#define WKL(F) F(0,0) F(0,1) F(0,2) F(0,3) F(1,0) F(1,1) F(1,2) F(1,3) \
  F(2,0) F(2,1) F(2,2) F(2,3) F(3,0) F(3,1) F(3,2) F(3,3)

__global__ __launch_bounds__(1024, 4) void lstm_rec(
    const int8_t* __restrict__ WAp,
    const __half* __restrict__ xgp,
    float* __restrict__ out)
{
    const int g = blockIdx.x;
    const int tid = threadIdx.x;
    const int w = tid >> 6;          // 0..15
    const int l = tid & 63;
    const int bl = l & 15;
    const int rg = l >> 4;

    __shared__ int8_t HB[2][4096];   // h_q double-buffered: [par][batch16][256 swizzled]

    // ---- int8 weight A-frags (16 x i32x4 = 64 regs, AGPR-friendly) ----
    const i32x4* wap = reinterpret_cast<const i32x4*>(WAp);
#define DECLW(mt, kt) i32x4 wq_##mt##_##kt = wap[(((4 * w + (mt)) * 4 + (kt)) * 64) + l];
    WKL(DECLW)
#undef DECLW

    // LDS read offsets (B-frags): slot = (kt*4+rg)^bl
    int ra[4];
#pragma unroll
    for (int kt = 0; kt < 4; ++kt)
        ra[kt] = bl * 256 + ((((kt * 4) + rg) ^ bl) & 15) * 16;
    // LDS write dword: slot = w^bl, dword = rg; bytes mt=0..3 packed in one u32
    const int wab = bl * 256 + ((w ^ bl) & 15) * 16 + rg * 4;

    i32x4 b0 = {0, 0, 0, 0}, b1 = b0, b2 = b0, b3 = b0;   // h_0 = 0
    float cs[4] = {0.f, 0.f, 0.f, 0.f};

    const __half* xp = xgp + ((size_t)(g * 16 + w) * 64 + l) * 16;
    f16x8 xA0 = *reinterpret_cast<const f16x8*>(xp);
    f16x8 xA1 = *reinterpret_cast<const f16x8*>(xp + 8);
    f16x8 xB0, xB1;

    float* op = out + (size_t)(16 * g + bl) * 256 + 16 * w + rg;

#define MFMT(mt) { \
        i32x4 acc = {0, 0, 0, 0}; \
        acc = __builtin_amdgcn_mfma_i32_16x16x64_i8(wq_##mt##_0, b0, acc, 0, 0, 0); \
        acc = __builtin_amdgcn_mfma_i32_16x16x64_i8(wq_##mt##_1, b1, acc, 0, 0, 0); \
        acc = __builtin_amdgcn_mfma_i32_16x16x64_i8(wq_##mt##_2, b2, acc, 0, 0, 0); \
        acc = __builtin_amdgcn_mfma_i32_16x16x64_i8(wq_##mt##_3, b3, acc, 0, 0, 0); \
        ac[mt] = acc; }

#define BODY(XC, XC1, XN, XN1, PAR, TNEXT) { \
        const __half* xq = xp + (size_t)(TNEXT) * 65536; \
        XN  = *reinterpret_cast<const f16x8*>(xq); \
        XN1 = *reinterpret_cast<const f16x8*>(xq + 8); \
        int8_t* HBB = HB[PAR]; \
        union { f16x8 v[2]; __half h[16]; } xu; xu.v[0] = XC; xu.v[1] = XC1; \
        i32x4 ac[4]; \
        MFMT(0) MFMT(1) MFMT(2) MFMT(3) \
        /* phase 1: pre-activations (independent) */ \
        float Ei[4], Ef[4], Eo[4], Ec[4]; \
        _Pragma("unroll") \
        for (int mt = 0; mt < 4; ++mt) { \
            float pi = fmaf((float)ac[mt][0], CSCI, (float)xu.h[mt * 4 + 0]); \
            float pf = fmaf((float)ac[mt][1], CSCI, (float)xu.h[mt * 4 + 1]); \
            float po = fmaf((float)ac[mt][2], CSCI, (float)xu.h[mt * 4 + 2]); \
            float pc = fminf(fmaf((float)ac[mt][3], CSCC, (float)xu.h[mt * 4 + 3]), 60.f); \
            Ei[mt] = EXP2(pi); Ef[mt] = EXP2(pf); Eo[mt] = EXP2(po); Ec[mt] = EXP2(pc); \
        } \
        /* phase 2: fused i/f rcp, cs update, h, quantize */ \
        uint32_t qm[4]; \
        float hv[4]; \
        _Pragma("unroll") \
        for (int mt = 0; mt < 4; ++mt) { \
            float D1 = (1.f + Ei[mt]) * (Ec[mt] + 1.f); \
            float D2 = 1.f + Ef[mt]; \
            float r  = RCP(D1 * D2); \
            float ic = (Ec[mt] - 1.f) * D2 * r; \
            float fg = D1 * r; \
            cs[mt] = fmaf(fg, cs[mt], ic); \
            float Fm = EXP2(fminf(2.88539008f * cs[mt], 60.f)); \
            float h2 = (Fm - 1.f) * RCP((1.f + Eo[mt]) * (Fm + 1.f)); \
            hv[mt] = h2; \
            qm[mt] = __float_as_uint(fmaf(h2, 127.f, 12582912.f)); \
        } \
        uint32_t p01 = __builtin_amdgcn_perm(qm[1], qm[0], 0x00000400u); \
        uint32_t p23 = __builtin_amdgcn_perm(qm[3], qm[2], 0x00000400u); \
        uint32_t pk  = __builtin_amdgcn_perm(p23, p01, 0x05040100u); \
        *reinterpret_cast<uint32_t*>(HBB + wab) = pk; \
        asm volatile("s_waitcnt lgkmcnt(0)\n\ts_barrier" ::: "memory"); \
        b0 = *reinterpret_cast<const i32x4*>(HBB + ra[0]); \
        b1 = *reinterpret_cast<const i32x4*>(HBB + ra[1]); \
        b2 = *reinterpret_cast<const i32x4*>(HBB + ra[2]); \
        b3 = *reinterpret_cast<const i32x4*>(HBB + ra[3]); \
        /* out-stores post-barrier: fill the ds_read/MFMA dependency bubble */ \
        op[0] = hv[0]; op[4] = hv[1]; op[8] = hv[2]; op[12] = hv[3]; \
        op += 16384; }

    for (int t2 = 0; t2 < 512; ++t2) {
        int te = 2 * t2;
        BODY(xA0, xA1, xB0, xB1, 1, te + 1)
        int tn = (te + 2 < 1024) ? (te + 2) : 1023;
        BODY(xB0, xB1, xA0, xA1, 0, tn)
    }
#undef BODY
#undef MFMT
}

// ---------------- launch ----------------
extern "C" void kernel_launch(void* const* d_in, const int* in_sizes, int n_in,
                              void* d_out, int out_size, void* d_ws, size_t ws_size,
                              hipStream_t stream)
{
    const float* x  = (const float*)d_in[0];
    const float* Wi = (const float*)d_in[1];
    const float* bi = (const float*)d_in[2];
    const float* Wf = (const float*)d_in[3];
    const float* bf = (const float*)d_in[4];
    const float* Wo = (const float*)d_in[5];
    const float* bo = (const float*)d_in[6];
    const float* Wc = (const float*)d_in[7];
    const float* bc = (const float*)d_in[8];

    char* ws = (char*)d_ws;
    __half*  xgh      = (__half*)(ws + XG_OFF);
    __half*  Ap       = (__half*)(ws + AP_OFF);
    __half*  Bp       = (__half*)(ws + BP_OFF);
    int8_t*  WAp      = (int8_t*)(ws + WAP_OFF);
    float*   bias_eff = (float*)(ws + BIAS_OFF);

    pack_weights<<<2052, 256, 0, stream>>>(Wi, Wf, Wo, Wc, bi, bf, bo, bc, WAp, Bp, bias_eff);
    pack_a<<<8192, 256, 0, stream>>>(x, Ap);
    gemm_xg<<<dim3(1024, 4), 256, 0, stream>>>(Ap, Bp, bias_eff, xgh);
    lstm_rec<<<4, 1024, 0, stream>>>(WAp, xgh, (float*)d_out);
}